// Round 2
// baseline (356.607 us; speedup 1.0000x reference)
//
#include <hip/hip_runtime.h>

#define T_LEN 2048
#define B_SZ  512
#define NIN   27

__device__ __forceinline__ float fast_exp2(float x) { return __builtin_amdgcn_exp2f(x); }
__device__ __forceinline__ float fast_rcp(float x)  { return __builtin_amdgcn_rcpf(x); }

// log2(e)
#define L2E 1.4426950408889634f

// async global->LDS, 16B per lane; LDS dest = uniform base + lane*16
#define GLDS(gptr, lptr)                                                          \
    __builtin_amdgcn_global_load_lds(                                             \
        (const __attribute__((address_space(1))) unsigned int*)(gptr),            \
        (__attribute__((address_space(3))) unsigned int*)(lptr), 16, 0, 0)

// ---------------------------------------------------------------------------
// Phase 1 (unchanged from R1 — isolating the scan variable this round):
// A[t*B+b] = pre-scaled gate pre-activations (float4).
// ---------------------------------------------------------------------------
__global__ __launch_bounds__(256) void lstm_proj(const float* __restrict__ x,
                                                 const float* __restrict__ Wih,
                                                 const float* __restrict__ bih,
                                                 const float* __restrict__ bhh,
                                                 float4* __restrict__ A) {
    __shared__ float xs[256 * NIN];             // 27648 B
    const int tid  = threadIdx.x;
    const size_t pos0 = (size_t)blockIdx.x * 256;

    const float4* src4 = (const float4*)(x + pos0 * NIN);
    float4* lds4 = (float4*)xs;
#pragma unroll
    for (int i = 0; i < 6; ++i) lds4[tid + i * 256] = src4[tid + i * 256];
    {
        int idx = tid + 6 * 256;
        if (idx < (256 * NIN) / 4) lds4[idx] = src4[idx];
    }

    float wreg[4 * NIN];
#pragma unroll
    for (int i = 0; i < NIN; ++i) ((float4*)wreg)[i] = ((const float4*)Wih)[i];

    float acc0 = bih[0] + bhh[0];
    float acc1 = bih[1] + bhh[1];
    float acc2 = bih[2] + bhh[2];
    float acc3 = bih[3] + bhh[3];

    __syncthreads();

    const float* xr = xs + tid * NIN;           // stride-27: 2-way bank alias = free
#pragma unroll
    for (int k = 0; k < NIN; ++k) {
        float xv = xr[k];
        acc0 = fmaf(xv, wreg[0 * NIN + k], acc0);
        acc1 = fmaf(xv, wreg[1 * NIN + k], acc1);
        acc2 = fmaf(xv, wreg[2 * NIN + k], acc2);
        acc3 = fmaf(xv, wreg[3 * NIN + k], acc3);
    }

    float4 o;
    o.x = -L2E * acc0;
    o.y = -L2E * acc1;
    o.z = -2.f * L2E * acc2;
    o.w = -L2E * acc3;
    A[pos0 + tid] = o;
}

// ---------------------------------------------------------------------------
// Phase 2 v2: 512 chains, 8 blocks x 1 wave. Double-buffered async LDS
// staging via global_load_lds + counted vmcnt(32); 8-step rolling ds_read
// register pipeline. Step arithmetic IDENTICAL to the passing R1 kernel.
// ---------------------------------------------------------------------------
#define CH 32

#define LSTM_STEP(a4, tt)                                                     \
    {                                                                         \
        float pi = fmaf(h, wi, (a4).x);                                       \
        float pf = fmaf(h, wf, (a4).y);                                       \
        float pg = fmaf(h, wg, (a4).z);                                       \
        float po = fmaf(h, wo, (a4).w);                                       \
        float ri = fast_rcp(1.f + fast_exp2(pi)); /* sigmoid(z_i) */          \
        float rf = fast_rcp(1.f + fast_exp2(pf)); /* sigmoid(z_f) */          \
        float rg = fast_rcp(1.f + fast_exp2(pg)); /* sigmoid(2 z_g) */        \
        float ro = fast_rcp(1.f + fast_exp2(po)); /* sigmoid(z_o) */          \
        float g  = fmaf(rg, 2.f, -1.f);           /* tanh(z_g) */             \
        c = fmaf(rf, c, ri * g);                                              \
        float rc = fast_rcp(1.f + fast_exp2(c * KN));                         \
        float th = fmaf(rc, 2.f, -1.f);           /* tanh(c) */               \
        h = ro * th;                                                          \
        out[(tt) * B_SZ + b] = h;                                             \
    }

__global__ __launch_bounds__(64) void lstm_scan(const float4* __restrict__ A,
                                                const float* __restrict__ Whh,
                                                float* __restrict__ out) {
    __shared__ float4 lds[2][CH][64];            // 64 KiB, double buffer
    const int lane = threadIdx.x;
    const int b = (blockIdx.x << 6) + lane;      // 0..511

    const float wi = -L2E * Whh[0];
    const float wf = -L2E * Whh[1];
    const float wg = -2.f * L2E * Whh[2];
    const float wo = -L2E * Whh[3];
    const float KN = -2.f * L2E;

    float h = 0.f, c = 0.f;

    const float4* Ab = A + b;                    // per-lane global base

    // Prologue: issue chunks 0 and 1 (64 loads in flight).
#pragma unroll
    for (int j = 0; j < CH; ++j) GLDS(Ab + (size_t)j * B_SZ, &lds[0][j][0]);
#pragma unroll
    for (int j = 0; j < CH; ++j) GLDS(Ab + (size_t)(CH + j) * B_SZ, &lds[1][j][0]);

    for (int n = 0; n < T_LEN / CH; ++n) {
        const int t0  = n * CH;
        const int buf = n & 1;

        // Counted wait: youngest 32 vmem ops are exactly next chunk's loads
        // (stores were issued before them; vmcnt retires FIFO), so this
        // guarantees chunk n's LDS data + all older stores are complete
        // while chunk n+1's loads stay in flight.
        asm volatile("s_waitcnt vmcnt(32)" ::: "memory");
        __builtin_amdgcn_sched_barrier(0);

        float4 ra[8], rb[8];
#pragma unroll
        for (int j = 0; j < 8; ++j) ra[j] = lds[buf][j][lane];

        // Rolling 8-step register pipeline over the 32-step chunk.
#pragma unroll
        for (int j = 0; j < 8; ++j) rb[j] = lds[buf][8 + j][lane];
#pragma unroll
        for (int j = 0; j < 8; ++j) LSTM_STEP(ra[j], t0 + j);

#pragma unroll
        for (int j = 0; j < 8; ++j) ra[j] = lds[buf][16 + j][lane];
#pragma unroll
        for (int j = 0; j < 8; ++j) LSTM_STEP(rb[j], t0 + 8 + j);

#pragma unroll
        for (int j = 0; j < 8; ++j) rb[j] = lds[buf][24 + j][lane];
#pragma unroll
        for (int j = 0; j < 8; ++j) LSTM_STEP(ra[j], t0 + 16 + j);

#pragma unroll
        for (int j = 0; j < 8; ++j) LSTM_STEP(rb[j], t0 + 24 + j);

        // Refill this buffer with chunk n+2 (issued AFTER all ds_reads of
        // this chunk, and after this chunk's stores -> youngest vmem ops).
        if (t0 + 2 * CH < T_LEN) {
#pragma unroll
            for (int j = 0; j < CH; ++j)
                GLDS(Ab + (size_t)(t0 + 2 * CH + j) * B_SZ, &lds[buf][j][0]);
        }
    }
}

// ---------------------------------------------------------------------------
extern "C" void kernel_launch(void* const* d_in, const int* in_sizes, int n_in,
                              void* d_out, int out_size, void* d_ws, size_t ws_size,
                              hipStream_t stream) {
    const float* x   = (const float*)d_in[0];  // (2048, 512, 27)
    const float* Wih = (const float*)d_in[1];  // (4, 27)
    const float* Whh = (const float*)d_in[2];  // (4, 1)
    const float* bih = (const float*)d_in[3];  // (4,)
    const float* bhh = (const float*)d_in[4];  // (4,)
    float* out = (float*)d_out;                // (2048, 512, 1)
    float4* A  = (float4*)d_ws;                // 16 MB workspace

    const int npos = T_LEN * B_SZ;
    lstm_proj<<<npos / 256, 256, 0, stream>>>(x, Wih, bih, bhh, A);
    lstm_scan<<<B_SZ / 64, 64, 0, stream>>>(A, Whh, out);
}

// Round 7
// 338.623 us; speedup vs baseline: 1.0531x; 1.0531x over previous
//
#include <hip/hip_runtime.h>

#define T_LEN 2048
#define B_SZ  512
#define NIN   27

__device__ __forceinline__ float fast_exp2(float x) { return __builtin_amdgcn_exp2f(x); }
__device__ __forceinline__ float fast_rcp(float x)  { return __builtin_amdgcn_rcpf(x); }

// log2(e)
#define L2E 1.4426950408889634f
#define KN  (-2.0f * L2E)

// DPP quad_perm broadcast of lane K within each 4-lane quad (VALU-only).
template<int K>
__device__ __forceinline__ float qbcast(float v) {
    constexpr int ctrl = K | (K << 2) | (K << 4) | (K << 6);   // quad_perm[K,K,K,K]
    return __int_as_float(
        __builtin_amdgcn_update_dpp(0, __float_as_int(v), ctrl, 0xf, 0xf, true));
}

// ---------------------------------------------------------------------------
// Phase 1 v2: low-VGPR projection.
// A[t*B+b] = float4 of pre-scaled gate pre-activations:
//   A.x = -z_i*L2E ; A.y = -z_f*L2E ; A.z = -2*z_g*L2E ; A.w = -z_o*L2E
// Weights staged ONCE per block into LDS transposed (wT[k] = gates for
// input k); k-loop reads them via uniform-address ds_read_b128 (broadcast,
// conflict-free). #pragma unroll 3 for ILP without register-hoisting all 27.
// VGPR ~35 -> 8 waves/SIMD; LDS 28080 B -> 5 blocks/CU.
// ---------------------------------------------------------------------------
__global__ __launch_bounds__(256) void lstm_proj(const float* __restrict__ x,
                                                 const float* __restrict__ Wih,
                                                 const float* __restrict__ bih,
                                                 const float* __restrict__ bhh,
                                                 float4* __restrict__ A) {
    __shared__ float  xs[256 * NIN];            // 27648 B
    __shared__ float4 wT[NIN];                  // 432 B, transposed weights
    const int tid  = threadIdx.x;
    const size_t pos0 = (size_t)blockIdx.x * 256;

    // Stage 256*27 floats = 1728 float4, perfectly coalesced.
    const float4* src4 = (const float4*)(x + pos0 * NIN);
    float4* lds4 = (float4*)xs;
#pragma unroll
    for (int i = 0; i < 6; ++i) lds4[tid + i * 256] = src4[tid + i * 256];
    {
        int idx = tid + 6 * 256;
        if (idx < (256 * NIN) / 4) lds4[idx] = src4[idx];
    }

    // Transposed weights -> LDS (27 threads, 4 scalar loads each; L2-hot).
    if (tid < NIN) {
        wT[tid] = make_float4(Wih[0 * NIN + tid], Wih[1 * NIN + tid],
                              Wih[2 * NIN + tid], Wih[3 * NIN + tid]);
    }

    // Uniform bias reads (8 scalar loads, issued before the barrier).
    float acc0 = bih[0] + bhh[0];
    float acc1 = bih[1] + bhh[1];
    float acc2 = bih[2] + bhh[2];
    float acc3 = bih[3] + bhh[3];

    __syncthreads();

    const float* xr = xs + tid * NIN;           // stride-27: 2-way alias = free
#pragma unroll 3
    for (int k = 0; k < NIN; ++k) {
        float  xv = xr[k];
        float4 w  = wT[k];                      // ds_read_b128, broadcast
        acc0 = fmaf(xv, w.x, acc0);
        acc1 = fmaf(xv, w.y, acc1);
        acc2 = fmaf(xv, w.z, acc2);
        acc3 = fmaf(xv, w.w, acc3);
    }

    float4 o;
    o.x = -L2E * acc0;
    o.y = -L2E * acc1;
    o.z = -2.f * L2E * acc2;
    o.w = -L2E * acc3;
    A[pos0 + tid] = o;                          // coalesced float4 store
}

// ---------------------------------------------------------------------------
// Phase 2 v3b: 4 lanes per chain (one gate per lane), 16 chains per wave,
// 32 waves total (1 per SIMD on 32 CUs) — all 512 chains in parallel, so
// total time = 2048 * chain-latency. Carried state: C = KN*c and pre (this
// step's scaled gate pre-activation). 4 trans ops/step; chain ~70 cy.
//   r  = rcp(1+exp2(pre));  rv = fma(r, S1, S0)
//   lane i: rv=KN*sig(z_i)  lane f: rv=sig(z_f)
//   lane g: rv=tanh(z_g)    lane o: rv=2*sig(z_o)
//   C' = fma(f, C, i*g);  r2 = rcp(1+exp2(C'))  [= sig(2c')]
//   h  = (2o)*(r2-0.5)   [off-chain, for store]
//   pre_next = fma(W*(2o), r2, fma(W*(2o), -0.5, a_next))
// ---------------------------------------------------------------------------
#define CH 16
#define NCHUNK (T_LEN / CH)   // 128

#define SCAN_STEP(vnext, tt)                                                  \
    {                                                                         \
        float e   = fast_exp2(pre);                                           \
        float r   = fast_rcp(e + 1.0f);                                       \
        float rv  = fmaf(r, S1, S0);                                          \
        float m_g  = qbcast<2>(rv);                                           \
        float m_i  = qbcast<0>(rv);                                           \
        float m_f  = qbcast<1>(rv);                                           \
        float m_o2 = qbcast<3>(rv);                                           \
        C = fmaf(m_f, C, m_i * m_g);                                          \
        float e2 = fast_exp2(C);                                              \
        float r2 = fast_rcp(e2 + 1.0f);                                       \
        float wm = W * m_o2;            /* in exp2/rcp shadow */              \
        float a2 = fmaf(wm, -0.5f, (vnext));                                  \
        float h  = m_o2 * (r2 - 0.5f);                                        \
        if (g == 0) out[(tt) * B_SZ + b] = h;                                 \
        pre = fmaf(wm, r2, a2);                                               \
    }

__global__ __launch_bounds__(64, 1) void lstm_scan(const float* __restrict__ Af,
                                                   const float* __restrict__ Whh,
                                                   float* __restrict__ out) {
    const int lane = threadIdx.x;              // 0..63
    const int g    = lane & 3;                 // gate index i,f,g,o
    const int b    = (blockIdx.x << 4) + (lane >> 2);   // chain id 0..511

    // Flat A element (t*512+b)*4+g = t*2048 + blockIdx*64 + lane.
    const float* src = Af + (size_t)(blockIdx.x << 6) + lane;

    const float sg = (g == 2) ? (-2.f * L2E) : (-L2E);
    const float W  = sg * Whh[g];
    const float S1 = (g == 0) ? KN : ((g == 1) ? 1.f : 2.f);
    const float S0 = (g == 2) ? -1.f : 0.f;

    float C = 0.f;

    float pa[CH], pb[CH];

    // Prologue: chunk 0 -> pa; pre_0 = a_0 (h0 = 0).
#pragma unroll
    for (int j = 0; j < CH; ++j) pa[j] = src[(size_t)j * 2048];
    float pre = pa[0];

    for (int n = 0; n < NCHUNK; n += 2) {
        const int t0 = n * CH;

        // Issue chunk n+1 loads, pinned before the compute block.
#pragma unroll
        for (int j = 0; j < CH; ++j) pb[j] = src[(size_t)(t0 + CH + j) * 2048];
        __builtin_amdgcn_sched_barrier(0);

#pragma unroll
        for (int j = 0; j < CH - 1; ++j) SCAN_STEP(pa[j + 1], t0 + j);
        SCAN_STEP(pb[0], t0 + CH - 1);

        // Issue chunk n+2 loads (guarded), then compute chunk n+1 from pb.
        if (n + 2 < NCHUNK) {
#pragma unroll
            for (int j = 0; j < CH; ++j) pa[j] = src[(size_t)(t0 + 2 * CH + j) * 2048];
        }
        __builtin_amdgcn_sched_barrier(0);

#pragma unroll
        for (int j = 0; j < CH - 1; ++j) SCAN_STEP(pb[j + 1], t0 + CH + j);
        // Last step: vnext = pa[0] of chunk n+2 (stale at tail -> pre dangles, unused).
        SCAN_STEP(pa[0], t0 + 2 * CH - 1);
    }
}

// ---------------------------------------------------------------------------
extern "C" void kernel_launch(void* const* d_in, const int* in_sizes, int n_in,
                              void* d_out, int out_size, void* d_ws, size_t ws_size,
                              hipStream_t stream) {
    const float* x   = (const float*)d_in[0];  // (2048, 512, 27)
    const float* Wih = (const float*)d_in[1];  // (4, 27)
    const float* Whh = (const float*)d_in[2];  // (4, 1)
    const float* bih = (const float*)d_in[3];  // (4,)
    const float* bhh = (const float*)d_in[4];  // (4,)
    float* out = (float*)d_out;                // (2048, 512, 1)
    float4* A  = (float4*)d_ws;                // 16 MB workspace

    const int npos = T_LEN * B_SZ;             // 1,048,576
    lstm_proj<<<npos / 256, 256, 0, stream>>>(x, Wih, bih, bhh, A);
    // 16 chains per block of 64 threads -> 512/16 = 32 blocks
    lstm_scan<<<B_SZ / 16, 64, 0, stream>>>((const float*)A, Whh, out);
}

// Round 9
// 311.695 us; speedup vs baseline: 1.1441x; 1.0864x over previous
//
#include <hip/hip_runtime.h>

#define T_LEN 2048
#define B_SZ  512
#define NIN   27

__device__ __forceinline__ float fast_exp2(float x) { return __builtin_amdgcn_exp2f(x); }
__device__ __forceinline__ float fast_rcp(float x)  { return __builtin_amdgcn_rcpf(x); }

// log2(e)
#define L2E 1.4426950408889634f
#define KN  (-2.0f * L2E)

// async global->LDS, 16B per lane; LDS dest = wave-uniform base + lane*16
#define GLDS(gptr, lptr)                                                          \
    __builtin_amdgcn_global_load_lds(                                             \
        (const __attribute__((address_space(1))) unsigned int*)(gptr),            \
        (__attribute__((address_space(3))) unsigned int*)(lptr), 16, 0, 0)

// DPP quad_perm broadcast of lane K within each 4-lane quad (VALU-only).
template<int K>
__device__ __forceinline__ float qbcast(float v) {
    constexpr int ctrl = K | (K << 2) | (K << 4) | (K << 6);   // quad_perm[K,K,K,K]
    return __int_as_float(
        __builtin_amdgcn_update_dpp(0, __float_as_int(v), ctrl, 0xf, 0xf, true));
}

// ---------------------------------------------------------------------------
// Phase 1 (BYTE-IDENTICAL to R7 — we need its counters, so no blind changes):
// A[t*B+b] = float4 of pre-scaled gate pre-activations.
// ---------------------------------------------------------------------------
__global__ __launch_bounds__(256) void lstm_proj(const float* __restrict__ x,
                                                 const float* __restrict__ Wih,
                                                 const float* __restrict__ bih,
                                                 const float* __restrict__ bhh,
                                                 float4* __restrict__ A) {
    __shared__ float  xs[256 * NIN];            // 27648 B
    __shared__ float4 wT[NIN];                  // 432 B, transposed weights
    const int tid  = threadIdx.x;
    const size_t pos0 = (size_t)blockIdx.x * 256;

    const float4* src4 = (const float4*)(x + pos0 * NIN);
    float4* lds4 = (float4*)xs;
#pragma unroll
    for (int i = 0; i < 6; ++i) lds4[tid + i * 256] = src4[tid + i * 256];
    {
        int idx = tid + 6 * 256;
        if (idx < (256 * NIN) / 4) lds4[idx] = src4[idx];
    }

    if (tid < NIN) {
        wT[tid] = make_float4(Wih[0 * NIN + tid], Wih[1 * NIN + tid],
                              Wih[2 * NIN + tid], Wih[3 * NIN + tid]);
    }

    float acc0 = bih[0] + bhh[0];
    float acc1 = bih[1] + bhh[1];
    float acc2 = bih[2] + bhh[2];
    float acc3 = bih[3] + bhh[3];

    __syncthreads();

    const float* xr = xs + tid * NIN;           // stride-27: 2-way alias = free
#pragma unroll 3
    for (int k = 0; k < NIN; ++k) {
        float  xv = xr[k];
        float4 w  = wT[k];
        acc0 = fmaf(xv, w.x, acc0);
        acc1 = fmaf(xv, w.y, acc1);
        acc2 = fmaf(xv, w.z, acc2);
        acc3 = fmaf(xv, w.w, acc3);
    }

    float4 o;
    o.x = -L2E * acc0;
    o.y = -L2E * acc1;
    o.z = -2.f * L2E * acc2;
    o.w = -L2E * acc3;
    A[pos0 + tid] = o;
}

// ---------------------------------------------------------------------------
// Phase 2 v4: v3b quad-split arithmetic (4 trans/step, carried-pre chain),
// but staging via global_load_lds (no VGPRs -> compiler CANNOT sink the
// global loads into the chain). Double-buffered 32-step chunks in LDS;
// one counted vmcnt(24) per chunk; 8-value ds_read bursts pinned with
// sched_barrier(0) so at worst cheap LDS latency touches the chain.
//
// vmcnt(24) proof: GLDS(chunk k) issued at end of chunk k-2's compute.
// Ops issued after it, before chunk k's first read: 3 blocks x 8 masked
// stores = 24. FIFO retire => "<=24 outstanding" == GLDS(k) landed, while
// GLDS(k+1) (not yet issued) and recent stores never block the pipe.
// ---------------------------------------------------------------------------
#define CHK  32
#define NCK  (T_LEN / CHK)    // 64

#define SCAN_STEP(vnext, tt)                                                  \
    {                                                                         \
        float e   = fast_exp2(pre);                                           \
        float r   = fast_rcp(e + 1.0f);                                       \
        float rv  = fmaf(r, S1, S0);                                          \
        float m_g  = qbcast<2>(rv);                                           \
        float m_i  = qbcast<0>(rv);                                           \
        float m_f  = qbcast<1>(rv);                                           \
        float m_o2 = qbcast<3>(rv);                                           \
        C = fmaf(m_f, C, m_i * m_g);                                          \
        float e2 = fast_exp2(C);                                              \
        float r2 = fast_rcp(e2 + 1.0f);                                       \
        float wm = W * m_o2;            /* in exp2/rcp shadow */              \
        float a2 = fmaf(wm, -0.5f, (vnext));                                  \
        float h  = m_o2 * (r2 - 0.5f);                                        \
        if (g == 0) out[(tt) * B_SZ + b] = h;                                 \
        pre = fmaf(wm, r2, a2);                                               \
    }

// burst-load 8 chunk values into regs, pinned before the following compute
#define BURST(reg, bufidx, base)                                              \
    {                                                                         \
        _Pragma("unroll")                                                     \
        for (int j = 0; j < 8; ++j) reg[j] = lds[bufidx][(base) + j][lane];   \
        __builtin_amdgcn_sched_barrier(0);                                    \
    }

// 8 steps: cur[j+1] feeds step j (j=0..6), nxt[0] feeds step 7
#define STEPS(cur, nxt, tbase)                                                \
    {                                                                         \
        _Pragma("unroll")                                                     \
        for (int j = 0; j < 7; ++j) SCAN_STEP(cur[j + 1], (tbase) + j);       \
        SCAN_STEP(nxt[0], (tbase) + 7);                                       \
    }

// issue the 8 GLDS staging one 32-step chunk c into buffer bufidx
#define ISSUE(c, bufidx)                                                      \
    {                                                                         \
        _Pragma("unroll")                                                     \
        for (int j = 0; j < 8; ++j)                                           \
            GLDS(wb + ((size_t)((c) * CHK + j * 4)) * 2048 + goff,            \
                 &lds[bufidx][j * 4][0]);                                     \
    }

__global__ __launch_bounds__(64, 1) void lstm_scan(const float* __restrict__ Af,
                                                   const float* __restrict__ Whh,
                                                   float* __restrict__ out) {
    __shared__ float lds[2][CHK][64];          // 16 KiB double buffer
    const int lane = threadIdx.x;              // 0..63
    const int g    = lane & 3;                 // gate index i,f,g,o
    const int b    = (blockIdx.x << 4) + (lane >> 2);   // chain id 0..511

    // Wave's 64-float row at time t: Af[t*2048 + (blockIdx<<6) + l].
    const float* wb = Af + (blockIdx.x << 6);
    // GLDS per-lane source offset: lane covers t-sub (lane>>4), floats (lane&15)*4.
    const size_t goff = (size_t)(lane >> 4) * 2048 + (size_t)(lane & 15) * 4;

    const float sg = (g == 2) ? (-2.f * L2E) : (-L2E);
    const float W  = sg * Whh[g];
    const float S1 = (g == 0) ? KN : ((g == 1) ? 1.f : 2.f);
    const float S0 = (g == 2) ? -1.f : 0.f;

    float C = 0.f;
    float ra[8], rb[8];

    // Prologue: stage chunks 0,1; wait chunk 0 only (8 = chunk 1 still flying).
    ISSUE(0, 0);
    ISSUE(1, 1);
    asm volatile("s_waitcnt vmcnt(8)" ::: "memory");
    __builtin_amdgcn_sched_barrier(0);
    BURST(ra, 0, 0);
    float pre = ra[0];                         // pre_0 = a_0 (h0 = 0)

    for (int c = 0; c < NCK; ++c) {
        const int buf = c & 1;
        const int t0  = c * CHK;
        // entry invariant: ra = a[t0 .. t0+7] in registers; chunk c landed.

        BURST(rb, buf, 8);
        STEPS(ra, rb, t0);

        BURST(ra, buf, 16);
        STEPS(rb, ra, t0 + 8);

        BURST(rb, buf, 24);
        STEPS(ra, rb, t0 + 16);

        // Chunk boundary: ensure chunk c+1 landed (<=24 younger ops possible).
        asm volatile("s_waitcnt vmcnt(24)" ::: "memory");
        __builtin_amdgcn_sched_barrier(0);
        BURST(ra, buf ^ 1, 0);                 // first 8 of chunk c+1 (c=63: dead)
        STEPS(rb, ra, t0 + 24);

        if (c + 2 < NCK) ISSUE(c + 2, buf);    // refill consumed buffer
    }
}

// ---------------------------------------------------------------------------
extern "C" void kernel_launch(void* const* d_in, const int* in_sizes, int n_in,
                              void* d_out, int out_size, void* d_ws, size_t ws_size,
                              hipStream_t stream) {
    const float* x   = (const float*)d_in[0];  // (2048, 512, 27)
    const float* Wih = (const float*)d_in[1];  // (4, 27)
    const float* Whh = (const float*)d_in[2];  // (4, 1)
    const float* bih = (const float*)d_in[3];  // (4,)
    const float* bhh = (const float*)d_in[4];  // (4,)
    float* out = (float*)d_out;                // (2048, 512, 1)
    float4* A  = (float4*)d_ws;                // 16 MB workspace

    const int npos = T_LEN * B_SZ;             // 1,048,576
    lstm_proj<<<npos / 256, 256, 0, stream>>>(x, Wih, bih, bhh, A);
    lstm_scan<<<B_SZ / 16, 64, 0, stream>>>((const float*)A, Whh, out);
}